// Round 2
// baseline (688.441 us; speedup 1.0000x reference)
//
#include <hip/hip_runtime.h>
#include <hip/hip_bf16.h>

// SepConv: relu -> dw3x3 -> pw1x1 -> BN (inference), NHWC fp32 in/out.
// B=16, H=W=224, C=96.

#define BATCH 16
#define HH 224
#define WWD 224
#define CC 96
#define NPIX (BATCH*HH*WWD)      // 802816
#define TILE 64                  // pixels per block
#define NBLK (NPIX/TILE)         // 12544 exactly
#define NTHREADS 384             // 6 waves
#define PAD 104                  // padded LDS row length (bf16 elems) -> 208 B

typedef __attribute__((ext_vector_type(8))) short short8;
typedef __attribute__((ext_vector_type(4))) float f32x4;

__device__ __forceinline__ unsigned short f2bf(float f){
    union{float f; unsigned u;} v; v.f = f;
    unsigned r = v.u + 0x7fffu + ((v.u >> 16) & 1u);   // RTNE
    return (unsigned short)(r >> 16);
}

__global__ __launch_bounds__(NTHREADS) void sepconv_kernel(
    const float* __restrict__ x,
    const float* __restrict__ dwk,    // (3,3,1,96)
    const float* __restrict__ dwb,    // (96)
    const float* __restrict__ pwk,    // (1,1,96,96) [ci][co]
    const float* __restrict__ pwb,    // (96)
    const float* __restrict__ gma,
    const float* __restrict__ bta,
    const float* __restrict__ mmean,
    const float* __restrict__ mvar,
    float* __restrict__ out)
{
    __shared__ __align__(16) unsigned short s_dw[TILE][PAD];   // dw output, bf16
    __shared__ __align__(16) unsigned short s_pwT[CC][PAD];    // pw^T: [co][ci], bf16
    __shared__ float s_scale[CC];
    __shared__ float s_shift[CC];

    const int t  = threadIdx.x;
    const int p0 = blockIdx.x * TILE;

    // ---- phase 0a: stage pw transposed into LDS as bf16 ----
    for (int e = t; e < CC*CC; e += NTHREADS) {
        int ci = e / CC;
        int co = e - ci*CC;
        s_pwT[co][ci] = f2bf(pwk[e]);
    }
    // ---- phase 0b: folded BN constants ----
    if (t < CC) {
        float g  = gma[t];
        float be = bta[t];
        float mu = mmean[t];
        float va = mvar[t];
        float pb = pwb[t];
        float sc = g / sqrtf(va + 1e-3f);
        s_scale[t] = sc;
        s_shift[t] = (pb - mu) * sc + be;
    }

    // ---- phase 1: relu + depthwise 3x3 (fp32) -> s_dw (bf16) ----
    // 64 px * 12 channel-groups(8) = 768 items; 2 per thread
    #pragma unroll
    for (int it = 0; it < 2; ++it) {
        int i  = t + it*NTHREADS;       // 0..767
        int px = i / 12;
        int cg = i - px*12;
        int c0 = cg*8;
        int p  = p0 + px;
        int b  = p / (HH*WWD);
        int rem = p - b*(HH*WWD);
        int h  = rem / WWD;
        int w  = rem - h*WWD;

        float acc[8];
        {
            float4 b0 = *reinterpret_cast<const float4*>(dwb + c0);
            float4 b1 = *reinterpret_cast<const float4*>(dwb + c0 + 4);
            acc[0]=b0.x; acc[1]=b0.y; acc[2]=b0.z; acc[3]=b0.w;
            acc[4]=b1.x; acc[5]=b1.y; acc[6]=b1.z; acc[7]=b1.w;
        }
        #pragma unroll
        for (int kh = -1; kh <= 1; ++kh) {
            int h2 = h + kh;
            if ((unsigned)h2 >= HH) continue;
            #pragma unroll
            for (int kw = -1; kw <= 1; ++kw) {
                int w2 = w + kw;
                if ((unsigned)w2 >= WWD) continue;
                const float* xp = x + (size_t)((b*HH + h2)*WWD + w2)*CC + c0;
                const float* wp = dwk + ((kh+1)*3 + (kw+1))*CC + c0;
                float4 x0 = *reinterpret_cast<const float4*>(xp);
                float4 x1 = *reinterpret_cast<const float4*>(xp + 4);
                float4 w0 = *reinterpret_cast<const float4*>(wp);
                float4 w1 = *reinterpret_cast<const float4*>(wp + 4);
                acc[0] += fmaxf(x0.x, 0.f) * w0.x;
                acc[1] += fmaxf(x0.y, 0.f) * w0.y;
                acc[2] += fmaxf(x0.z, 0.f) * w0.z;
                acc[3] += fmaxf(x0.w, 0.f) * w0.w;
                acc[4] += fmaxf(x1.x, 0.f) * w1.x;
                acc[5] += fmaxf(x1.y, 0.f) * w1.y;
                acc[6] += fmaxf(x1.z, 0.f) * w1.z;
                acc[7] += fmaxf(x1.w, 0.f) * w1.w;
            }
        }
        uint4 sv;
        sv.x = (unsigned)f2bf(acc[0]) | ((unsigned)f2bf(acc[1]) << 16);
        sv.y = (unsigned)f2bf(acc[2]) | ((unsigned)f2bf(acc[3]) << 16);
        sv.z = (unsigned)f2bf(acc[4]) | ((unsigned)f2bf(acc[5]) << 16);
        sv.w = (unsigned)f2bf(acc[6]) | ((unsigned)f2bf(acc[7]) << 16);
        *reinterpret_cast<uint4*>(&s_dw[px][c0]) = sv;
    }

    __syncthreads();

    // ---- phase 2: pointwise GEMM via MFMA 16x16x32 bf16 + BN epilogue ----
    // out[px][co] = sum_ci dw[px][ci] * pw[ci][co]
    // wave handles co block 16*wave for all 4 m-tiles; K = 96 = 3 steps of 32.
    const int wave = t >> 6;
    const int lane = t & 63;
    const int col  = lane & 15;       // n for B, m for A, col for D
    const int quad = lane >> 4;
    const int co   = wave*16 + col;

    short8 bfr[3];
    #pragma unroll
    for (int ks = 0; ks < 3; ++ks)
        bfr[ks] = *reinterpret_cast<const short8*>(&s_pwT[co][ks*32 + quad*8]);

    const float sc = s_scale[co];
    const float sh = s_shift[co];

    #pragma unroll
    for (int mt = 0; mt < 4; ++mt) {
        f32x4 acc = {0.f, 0.f, 0.f, 0.f};
        #pragma unroll
        for (int ks = 0; ks < 3; ++ks) {
            short8 afr = *reinterpret_cast<const short8*>(&s_dw[mt*16 + col][ks*32 + quad*8]);
            acc = __builtin_amdgcn_mfma_f32_16x16x32_bf16(afr, bfr[ks], acc, 0, 0, 0);
        }
        int prow = p0 + mt*16 + quad*4;
        #pragma unroll
        for (int r = 0; r < 4; ++r) {
            float v = acc[r]*sc + sh;
            out[(size_t)(prow + r)*CC + co] = v;
        }
    }
}

extern "C" void kernel_launch(void* const* d_in, const int* in_sizes, int n_in,
                              void* d_out, int out_size, void* d_ws, size_t ws_size,
                              hipStream_t stream)
{
    sepconv_kernel<<<NBLK, NTHREADS, 0, stream>>>(
        (const float*)d_in[0],
        (const float*)d_in[1],
        (const float*)d_in[2],
        (const float*)d_in[3],
        (const float*)d_in[4],
        (const float*)d_in[5],
        (const float*)d_in[6],
        (const float*)d_in[7],
        (const float*)d_in[8],
        (float*)d_out);
}